// Round 5
// baseline (328.716 us; speedup 1.0000x reference)
//
#include <hip/hip_runtime.h>
#include <math.h>

typedef unsigned short ushort_t;
typedef unsigned int   uint_t;
typedef unsigned long long ull_t;
typedef __attribute__((ext_vector_type(8))) short bf16x8;
typedef __attribute__((ext_vector_type(4))) float f32x4;

#define NPTS   65536   // B*P
#define NV     5023
#define LATD   32
#define KF     110     // real feature dim (padded to 128 with zeros at stage time)
#define VSEGS  4
#define SEGLEN 1256    // ceil(NV/VSEGS)

__device__ __forceinline__ ushort_t f2bf(float f) {
  union { float f; unsigned u; } x; x.f = f;
  unsigned r = x.u + 0x7fffu + ((x.u >> 16) & 1u);   // RNE
  return (ushort_t)(r >> 16);
}
__device__ __forceinline__ float bf2f(ushort_t u) {
  union { unsigned u; float f; } x; x.u = ((unsigned)u) << 16;
  return x.f;
}
__device__ __forceinline__ uint_t packsplit(float v) {
  const ushort_t h = f2bf(v);
  const ushort_t l = f2bf(v - bf2f(h));
  return (uint_t)h | ((uint_t)l << 16);
}

// ------------- Kernel 1: NN search, vertex-split, u64 atomicMin publish -------------
// grid 1024 = 256 pt-blocks x 4 vertex segments; 8 pts/thread, 8-way split in-wave.
__global__ __launch_bounds__(256) void k_nn(
    const float* __restrict__ pts, const float* __restrict__ dm,
    ull_t* __restrict__ pack)
{
  __shared__ float4 sV[512];
  const int tid   = threadIdx.x;
  const int ptblk = blockIdx.x >> 2, vseg = blockIdx.x & 3;
  const int s     = tid & 7;
  const int pbase = ptblk * 256 + (tid >> 3) * 8;
  const int b     = ptblk >> 7;                    // 128 pt-blocks per batch
  const float* __restrict__ dmb = dm + b * NV * 3;
  const int v_lo = vseg * SEGLEN;
  const int v_hi = (v_lo + SEGLEN < NV) ? v_lo + SEGLEN : NV;

  float px[8], py[8], pz[8], p2[8], best[8]; int bidx[8];
  #pragma unroll
  for (int j = 0; j < 8; ++j) {
    px[j] = pts[(pbase+j)*3+0]; py[j] = pts[(pbase+j)*3+1]; pz[j] = pts[(pbase+j)*3+2];
    p2[j] = fmaf(px[j],px[j], fmaf(py[j],py[j], pz[j]*pz[j]));
    best[j] = 3.4e38f; bidx[j] = 0;
  }

  for (int v0 = v_lo; v0 < v_hi; v0 += 512) {
    __syncthreads();
    for (int i = tid; i < 512; i += 256) {
      const int v = v0 + i;
      float4 t;
      if (v < v_hi) {
        const float x = dmb[v*3+0], y = dmb[v*3+1], z = dmb[v*3+2];
        t = make_float4(x, y, z, fmaf(x,x, fmaf(y,y, z*z)));
      } else {
        t = make_float4(0.f, 0.f, 0.f, __builtin_inff());   // d2=inf, never wins
      }
      sV[i] = t;
    }
    __syncthreads();
    #pragma unroll 4
    for (int k = 0; k < 64; ++k) {
      const float4 t = sV[k*8 + s];
      const int vi = v0 + k*8 + s;
      #pragma unroll
      for (int j = 0; j < 8; ++j) {
        const float dot = fmaf(px[j], t.x, fmaf(py[j], t.y, pz[j]*t.z));
        float d2 = fmaf(-2.f, dot, p2[j] + t.w);
        d2 = fmaxf(d2, 0.f);
        if (d2 < best[j]) { best[j] = d2; bidx[j] = vi; }
      }
    }
  }

  // reduce over the 8 in-wave splits: lexicographic (d2, idx) min
  #pragma unroll
  for (int off = 1; off <= 4; off <<= 1) {
    #pragma unroll
    for (int j = 0; j < 8; ++j) {
      const float ob = __shfl_xor(best[j], off, 64);
      const int   oi = __shfl_xor(bidx[j], off, 64);
      const bool take = (ob < best[j]) || ((ob == best[j]) && (oi < bidx[j]));
      if (take) { best[j] = ob; bidx[j] = oi; }
    }
  }
  float bb = best[0]; int bi = bidx[0];
  #pragma unroll
  for (int j = 1; j < 8; ++j) if (s == j) { bb = best[j]; bi = bidx[j]; }

  const int g = ptblk * 256 + tid;
  const ull_t pv = ((ull_t)__float_as_uint(bb) << 32) | (uint_t)bi;
  atomicMin(&pack[g], pv);
}

// ------------- Kernel 2: features from NN winner (+ weight hi/lo prep) -------------
// Weight panel offsets (ushort units per plane), all K=128 x N=128:
// L0:0 L1:16384 L2:32768 L3:49152 L4a(initial):65536 L4b(x):81920 L5:98304 L6:114688 L7:131072
__global__ __launch_bounds__(256) void k_feat(
    const float* __restrict__ pts, const float* __restrict__ dm,
    const float* __restrict__ cano, const float* __restrict__ lat,
    const ull_t* __restrict__ pack,
    const float* __restrict__ w0, const float* __restrict__ w1,
    const float* __restrict__ w2, const float* __restrict__ w3,
    const float* __restrict__ w4, const float* __restrict__ w5,
    const float* __restrict__ w6, const float* __restrict__ w7,
    uint_t* __restrict__ wsIp, float* __restrict__ base3,
    ushort_t* __restrict__ wsWh, ushort_t* __restrict__ wsWl)
{
  const int tid = threadIdx.x;

  if (blockIdx.x >= 256) {   // ---- weight prep: fp32 -> bf16 hi/lo, zero-padded ----
    const int l = blockIdx.x - 256;
    const float* Wsrc[8] = {w0,w1,w2,w3,w4,w5,w6,w7};
    const float* __restrict__ src = Wsrc[l];
    const int Kp = (l == 4) ? 256 : 128;
    const int tot = 128 * Kp;
    for (int idx = tid; idx < tot; idx += 256) {
      const int n = idx / Kp, k = idx - n * Kp;
      float v; int dst;
      if (l == 4) {
        if (k < 128) { dst = 65536 + n*128 + k;        v = (k < KF) ? src[n*238 + k] : 0.f; }
        else         { dst = 81920 + n*128 + (k-128);  v = src[n*238 + KF + (k-128)]; }
      } else {
        dst = ((l < 4) ? l*16384 : 98304 + (l-5)*16384) + n*128 + k;
        v = (l == 0) ? ((k < KF) ? src[n*110 + k] : 0.f) : src[n*128 + k];
      }
      const ushort_t h = f2bf(v);
      wsWh[dst] = h;
      wsWl[dst] = f2bf(v - bf2f(h));
    }
    return;
  }

  const int g = blockIdx.x * 256 + tid;
  const int b = g >> 15;
  const float* __restrict__ dmb = dm + b * NV * 3;

  const ull_t pv = pack[g];
  const int   bi = (int)(pv & 0xffffffffull);
  const float bb = __uint_as_float((uint_t)(pv >> 32));

  const float qx = pts[g*3+0], qy = pts[g*3+1], qz = pts[g*3+2];
  const float wgt = expf(-bb);
  const float sx = (cano[bi*3+0] - dmb[bi*3+0]) * wgt;
  const float sy = (cano[bi*3+1] - dmb[bi*3+1]) * wgt;
  const float sz = (cano[bi*3+2] - dmb[bi*3+2]) * wgt;

  base3[g*3+0] = qx + sx;
  base3[g*3+1] = qy + sy;
  base3[g*3+2] = qz + sz;

  wsIp[0*(size_t)NPTS+g] = packsplit(qx);
  wsIp[1*(size_t)NPTS+g] = packsplit(qy);
  wsIp[2*(size_t)NPTS+g] = packsplit(qz);
  int k = 3;
  #pragma unroll
  for (int f = 0; f < 10; ++f) {
    const float F = (float)(1 << f);
    float s0,c0,s1,c1,s2,c2;
    sincosf(qx*F,&s0,&c0); sincosf(qy*F,&s1,&c1); sincosf(qz*F,&s2,&c2);
    wsIp[(size_t)(k+0)*NPTS+g]=packsplit(s0); wsIp[(size_t)(k+1)*NPTS+g]=packsplit(s1);
    wsIp[(size_t)(k+2)*NPTS+g]=packsplit(s2); wsIp[(size_t)(k+3)*NPTS+g]=packsplit(c0);
    wsIp[(size_t)(k+4)*NPTS+g]=packsplit(c1); wsIp[(size_t)(k+5)*NPTS+g]=packsplit(c2);
    k += 6;
  }
  wsIp[63*(size_t)NPTS+g]=packsplit(sx); wsIp[64*(size_t)NPTS+g]=packsplit(sy);
  wsIp[65*(size_t)NPTS+g]=packsplit(sz);
  k = 66;
  #pragma unroll
  for (int f = 0; f < 2; ++f) {
    const float F = (float)(1 << f);
    float s0,c0,s1,c1,s2,c2;
    sincosf(sx*F,&s0,&c0); sincosf(sy*F,&s1,&c1); sincosf(sz*F,&s2,&c2);
    wsIp[(size_t)(k+0)*NPTS+g]=packsplit(s0); wsIp[(size_t)(k+1)*NPTS+g]=packsplit(s1);
    wsIp[(size_t)(k+2)*NPTS+g]=packsplit(s2); wsIp[(size_t)(k+3)*NPTS+g]=packsplit(c0);
    wsIp[(size_t)(k+4)*NPTS+g]=packsplit(c1); wsIp[(size_t)(k+5)*NPTS+g]=packsplit(c2);
    k += 6;
  }
  #pragma unroll
  for (int j = 0; j < LATD; ++j) wsIp[(size_t)(78+j)*NPTS + g] = packsplit(lat[g*LATD + j]);
}

// ------------- Kernel 3: fused MLP, bf16 hi/lo 3-term MFMA (unchanged from r4) -------------
__device__ __forceinline__ void stage_W(ushort_t* __restrict__ sWh, ushort_t* __restrict__ sWl,
    const ushort_t* __restrict__ gh0, const ushort_t* __restrict__ gl0, int tid)
{
  const uint4* __restrict__ gh = (const uint4*)gh0;
  const uint4* __restrict__ gl = (const uint4*)gl0;
  #pragma unroll
  for (int it = 0; it < 4; ++it) {
    const int c = it*512 + tid;
    const int n = c >> 4, kb = c & 15;
    *(uint4*)(sWh + n*136 + kb*8) = gh[c];
    *(uint4*)(sWl + n*136 + kb*8) = gl[c];
  }
}

__device__ __forceinline__ void stage_X(ushort_t* __restrict__ sXh, ushort_t* __restrict__ sXl,
    const uint_t* __restrict__ wsIp, int g0, int tid)
{
  #pragma unroll
  for (int it = 0; it < 32; ++it) {
    const int idx = it*512 + tid;
    const int k = idx >> 7, m = idx & 127;
    uint_t u = 0;
    if (k < KF) u = wsIp[(size_t)k*NPTS + g0 + m];
    sXh[m*136 + k] = (ushort_t)(u & 0xffffu);
    sXl[m*136 + k] = (ushort_t)(u >> 16);
  }
}

__device__ __forceinline__ void zero_acc(f32x4 (&acc)[4][2]) {
  #pragma unroll
  for (int i = 0; i < 4; ++i)
    #pragma unroll
    for (int j = 0; j < 2; ++j)
      acc[i][j] = (f32x4){0.f,0.f,0.f,0.f};
}

__device__ __forceinline__ void mfma_panel(f32x4 (&acc)[4][2],
    const ushort_t* __restrict__ sXh, const ushort_t* __restrict__ sXl,
    const ushort_t* __restrict__ sWh, const ushort_t* __restrict__ sWl,
    int mq, int nq, int l15, int kq)
{
  #pragma unroll
  for (int ks = 0; ks < 4; ++ks) {
    const int ko = ks*32 + kq;
    bf16x8 bh[2], bl[2], ah[4], al[4];
    #pragma unroll
    for (int nt = 0; nt < 2; ++nt) {
      const int n = nq*32 + nt*16 + l15;
      bh[nt] = *(const bf16x8*)(sWh + n*136 + ko);
      bl[nt] = *(const bf16x8*)(sWl + n*136 + ko);
    }
    #pragma unroll
    for (int mt = 0; mt < 4; ++mt) {
      const int m = mq*64 + mt*16 + l15;
      ah[mt] = *(const bf16x8*)(sXh + m*136 + ko);
      al[mt] = *(const bf16x8*)(sXl + m*136 + ko);
    }
    #pragma unroll
    for (int mt = 0; mt < 4; ++mt)
      #pragma unroll
      for (int nt = 0; nt < 2; ++nt) {
        acc[mt][nt] = __builtin_amdgcn_mfma_f32_16x16x32_bf16(ah[mt], bh[nt], acc[mt][nt], 0,0,0);
        acc[mt][nt] = __builtin_amdgcn_mfma_f32_16x16x32_bf16(al[mt], bh[nt], acc[mt][nt], 0,0,0);
        acc[mt][nt] = __builtin_amdgcn_mfma_f32_16x16x32_bf16(ah[mt], bl[nt], acc[mt][nt], 0,0,0);
      }
  }
}

__device__ __forceinline__ void epi_relu_split(f32x4 (&acc)[4][2],
    ushort_t* __restrict__ sXh, ushort_t* __restrict__ sXl,
    const float* __restrict__ bias, int mq, int nq, int quad, int l15)
{
  #pragma unroll
  for (int mt = 0; mt < 4; ++mt)
    #pragma unroll
    for (int nt = 0; nt < 2; ++nt) {
      const int n = nq*32 + nt*16 + l15;
      const float bv = bias[n];
      #pragma unroll
      for (int r = 0; r < 4; ++r) {
        const int m = mq*64 + mt*16 + quad*4 + r;
        const float v = fmaxf(acc[mt][nt][r] + bv, 0.f);
        const ushort_t h = f2bf(v);
        sXh[m*136 + n] = h;
        sXl[m*136 + n] = f2bf(v - bf2f(h));
      }
    }
}

__global__ __launch_bounds__(512) void k_mlp(
    const uint_t* __restrict__ wsIp, const float* __restrict__ base3,
    const ushort_t* __restrict__ wsWh, const ushort_t* __restrict__ wsWl,
    const float* __restrict__ b0, const float* __restrict__ b1,
    const float* __restrict__ b2, const float* __restrict__ b3,
    const float* __restrict__ b4, const float* __restrict__ b5,
    const float* __restrict__ b6, const float* __restrict__ b7,
    const float* __restrict__ w_out, const float* __restrict__ b_out,
    float* __restrict__ out)
{
  __shared__ __align__(16) ushort_t sXh[128*136];
  __shared__ __align__(16) ushort_t sXl[128*136];
  __shared__ __align__(16) ushort_t sW2[2*128*136];
  __shared__ float sB[8*128 + 384 + 4];

  ushort_t* sWh = sW2;
  ushort_t* sWl = sW2 + 128*136;

  const int tid  = threadIdx.x;
  const int lane = tid & 63, wid = tid >> 6;
  const int quad = lane >> 4, l15 = lane & 15, kq = quad*8;
  const int mq = wid & 1, nq = wid >> 1;
  const int g0 = blockIdx.x * 128;

  f32x4 acc[4][2];

  stage_W(sWh, sWl, wsWh + 0, wsWl + 0, tid);
  stage_X(sXh, sXl, wsIp, g0, tid);
  {
    const float* bs[8] = {b0,b1,b2,b3,b4,b5,b6,b7};
    if (tid < 128) {
      #pragma unroll
      for (int l = 0; l < 8; ++l) sB[l*128 + tid] = bs[l][tid];
    } else {
      sB[1024 + (tid - 128)] = w_out[tid - 128];
    }
    if (tid < 3) sB[1408 + tid] = b_out[tid];
  }
  __syncthreads();
  zero_acc(acc);
  mfma_panel(acc, sXh, sXl, sWh, sWl, mq, nq, l15, kq);
  __syncthreads();
  epi_relu_split(acc, sXh, sXl, sB + 0, mq, nq, quad, l15);

  for (int l = 1; l <= 3; ++l) {
    __syncthreads();
    stage_W(sWh, sWl, wsWh + l*16384, wsWl + l*16384, tid);
    __syncthreads();
    zero_acc(acc);
    mfma_panel(acc, sXh, sXl, sWh, sWl, mq, nq, l15, kq);
    __syncthreads();
    epi_relu_split(acc, sXh, sXl, sB + l*128, mq, nq, quad, l15);
  }

  __syncthreads();
  stage_W(sWh, sWl, wsWh + 81920, wsWl + 81920, tid);
  __syncthreads();
  zero_acc(acc);
  mfma_panel(acc, sXh, sXl, sWh, sWl, mq, nq, l15, kq);

  __syncthreads();
  stage_W(sWh, sWl, wsWh + 65536, wsWl + 65536, tid);
  stage_X(sXh, sXl, wsIp, g0, tid);
  __syncthreads();
  mfma_panel(acc, sXh, sXl, sWh, sWl, mq, nq, l15, kq);
  __syncthreads();
  epi_relu_split(acc, sXh, sXl, sB + 4*128, mq, nq, quad, l15);

  for (int l = 5; l <= 6; ++l) {
    __syncthreads();
    stage_W(sWh, sWl, wsWh + 98304 + (l-5)*16384, wsWl + 98304 + (l-5)*16384, tid);
    __syncthreads();
    zero_acc(acc);
    mfma_panel(acc, sXh, sXl, sWh, sWl, mq, nq, l15, kq);
    __syncthreads();
    epi_relu_split(acc, sXh, sXl, sB + l*128, mq, nq, quad, l15);
  }

  __syncthreads();
  stage_W(sWh, sWl, wsWh + 131072, wsWl + 131072, tid);
  __syncthreads();
  zero_acc(acc);
  mfma_panel(acc, sXh, sXl, sWh, sWl, mq, nq, l15, kq);

  float* __restrict__ out1 = out + (size_t)NPTS*3;
  #pragma unroll
  for (int mt = 0; mt < 4; ++mt)
    #pragma unroll
    for (int nt = 0; nt < 2; ++nt) {
      const int n = nq*32 + nt*16 + l15;
      const float bv = sB[7*128 + n];
      #pragma unroll
      for (int r = 0; r < 4; ++r) {
        const int m = mq*64 + mt*16 + quad*4 + r;
        const float v = acc[mt][nt][r] + bv;
        out1[(size_t)(g0 + m)*128 + n] = v;
        acc[mt][nt][r] = fmaxf(v, 0.f);
      }
    }

  __syncthreads();
  float* __restrict__ sF = (float*)sW2;
  #pragma unroll
  for (int mt = 0; mt < 4; ++mt)
    #pragma unroll
    for (int nt = 0; nt < 2; ++nt) {
      const int n = nq*32 + nt*16 + l15;
      #pragma unroll
      for (int r = 0; r < 4; ++r) {
        const int m = mq*64 + mt*16 + quad*4 + r;
        sF[m*132 + n] = acc[mt][nt][r];
      }
    }
  __syncthreads();

  if (tid < 384) {
    const int m = tid / 3, c = tid - m*3;
    const float* __restrict__ xr = sF + m*132;
    const float* __restrict__ wc = sB + 1024 + c*128;
    float a = 0.f;
    #pragma unroll 8
    for (int k = 0; k < 128; ++k) a = fmaf(xr[k], wc[k], a);
    const int g = g0 + m;
    out[g*3 + c] = base3[g*3 + c] + a + sB[1408 + c];
  }
}

extern "C" void kernel_launch(void* const* d_in, const int* in_sizes, int n_in,
                              void* d_out, int out_size, void* d_ws, size_t ws_size,
                              hipStream_t stream)
{
  const float* pts  = (const float*)d_in[0];
  const float* dm   = (const float*)d_in[1];
  const float* cano = (const float*)d_in[2];
  const float* lat  = (const float*)d_in[3];
  const float* w[8]; const float* b[8];
  for (int i = 0; i < 8; ++i) {
    w[i] = (const float*)d_in[4 + 2*i];
    b[i] = (const float*)d_in[5 + 2*i];
  }
  const float* w_out = (const float*)d_in[20];
  const float* b_out = (const float*)d_in[21];
  float* out = (float*)d_out;

  // ws: wsIp [110][NPTS] uint (28.84MB) | base3 (786KB) | wsWh (288KB) | wsWl (288KB) | pack (512KB)
  uint_t*   wsIp  = (uint_t*)d_ws;
  float*    base3 = (float*)((char*)d_ws + (size_t)KF*NPTS*4);
  ushort_t* wsWh  = (ushort_t*)((char*)base3 + (size_t)NPTS*3*4);
  ushort_t* wsWl  = wsWh + 147456;
  ull_t*    pack  = (ull_t*)(wsWl + 147456);

  hipMemsetAsync(pack, 0xFF, (size_t)NPTS*8, stream);
  k_nn<<<256*VSEGS, 256, 0, stream>>>(pts, dm, pack);
  k_feat<<<256 + 8, 256, 0, stream>>>(pts, dm, cano, lat, pack,
      w[0],w[1],w[2],w[3],w[4],w[5],w[6],w[7], wsIp, base3, wsWh, wsWl);
  k_mlp<<<NPTS/128, 512, 0, stream>>>(wsIp, base3, wsWh, wsWl,
      b[0],b[1],b[2],b[3],b[4],b[5],b[6],b[7], w_out, b_out, out);
}

// Round 6
// 301.428 us; speedup vs baseline: 1.0905x; 1.0905x over previous
//
#include <hip/hip_runtime.h>
#include <math.h>

typedef unsigned short ushort_t;
typedef unsigned int   uint_t;
typedef unsigned long long ull_t;
typedef __attribute__((ext_vector_type(8))) short bf16x8;
typedef __attribute__((ext_vector_type(4))) float f32x4;

#define NPTS   65536   // B*P
#define NV     5023
#define LATD   32
#define KF     110
#define SEGLEN 1256    // ceil(NV/4)

__device__ __forceinline__ ushort_t f2bf(float f) {
  union { float f; unsigned u; } x; x.f = f;
  unsigned r = x.u + 0x7fffu + ((x.u >> 16) & 1u);   // RNE
  return (ushort_t)(r >> 16);
}
__device__ __forceinline__ float bf2f(ushort_t u) {
  union { unsigned u; float f; } x; x.u = ((unsigned)u) << 16;
  return x.f;
}
__device__ __forceinline__ uint_t packsplit(float v) {
  const ushort_t h = f2bf(v);
  const ushort_t l = f2bf(v - bf2f(h));
  return (uint_t)h | ((uint_t)l << 16);
}

// Weight panel offsets (ushort units per plane), all K=128 x N=128 row-major [n][k]:
// L0:0 L1:16384 L2:32768 L3:49152 L4a(initial):65536 L4b(x):81920 L5:98304 L6:114688 L7:131072

// ------------- Kernel 1: fused NN (in-block 4-seg split) + sliced features -------------
// blocks 0..255: 1024 threads = 4 segments x 256; then 4 slices x 256 points.
// blocks 256..263: weight prep.
__global__ __launch_bounds__(1024) void k_nnfeat(
    const float* __restrict__ pts, const float* __restrict__ dm,
    const float* __restrict__ cano, const float* __restrict__ lat,
    const float* __restrict__ w0, const float* __restrict__ w1,
    const float* __restrict__ w2, const float* __restrict__ w3,
    const float* __restrict__ w4, const float* __restrict__ w5,
    const float* __restrict__ w6, const float* __restrict__ w7,
    uint_t* __restrict__ wsIp, float* __restrict__ base3,
    ushort_t* __restrict__ wsWh, ushort_t* __restrict__ wsWl)
{
  const int tid = threadIdx.x;

  if (blockIdx.x >= 256) {   // ---- weight prep: fp32 -> bf16 hi/lo, zero-padded ----
    const int l = blockIdx.x - 256;
    const float* Wsrc[8] = {w0,w1,w2,w3,w4,w5,w6,w7};
    const float* __restrict__ src = Wsrc[l];
    const int Kp = (l == 4) ? 256 : 128;
    const int tot = 128 * Kp;
    for (int idx = tid; idx < tot; idx += 1024) {
      const int n = idx / Kp, k = idx - n * Kp;
      float v; int dst;
      if (l == 4) {
        if (k < 128) { dst = 65536 + n*128 + k;        v = (k < KF) ? src[n*238 + k] : 0.f; }
        else         { dst = 81920 + n*128 + (k-128);  v = src[n*238 + KF + (k-128)]; }
      } else {
        dst = ((l < 4) ? l*16384 : 98304 + (l-5)*16384) + n*128 + k;
        v = (l == 0) ? ((k < KF) ? src[n*110 + k] : 0.f) : src[n*128 + k];
      }
      const ushort_t h = f2bf(v);
      wsWh[dst] = h;
      wsWl[dst] = f2bf(v - bf2f(h));
    }
    return;
  }

  __shared__ float4 sV[4*512];     // 32 KB, one 512-vert chunk per segment
  __shared__ ull_t  sRed[4*256];   // 8 KB, per-segment winners

  const int seg = tid >> 8, st = tid & 255;
  const int s   = st & 7;
  const int pbase = blockIdx.x * 256 + (st >> 3) * 8;
  const int b   = blockIdx.x >> 7;
  const float* __restrict__ dmb = dm + b * NV * 3;
  const int v_lo = seg * SEGLEN;
  const int v_hi = (v_lo + SEGLEN < NV) ? v_lo + SEGLEN : NV;

  float px[8], py[8], pz[8], p2[8], best[8]; int bidx[8];
  #pragma unroll
  for (int j = 0; j < 8; ++j) {
    px[j] = pts[(pbase+j)*3+0]; py[j] = pts[(pbase+j)*3+1]; pz[j] = pts[(pbase+j)*3+2];
    p2[j] = fmaf(px[j],px[j], fmaf(py[j],py[j], pz[j]*pz[j]));
    best[j] = 3.4e38f; bidx[j] = 0;
  }

  #pragma unroll
  for (int c = 0; c < 3; ++c) {            // 3 chunks cover SEGLEN=1256
    const int v0 = v_lo + c*512;
    __syncthreads();
    for (int i = st; i < 512; i += 256) {
      const int v = v0 + i;
      float4 t;
      if (v < v_hi) {
        const float x = dmb[v*3+0], y = dmb[v*3+1], z = dmb[v*3+2];
        t = make_float4(x, y, z, fmaf(x,x, fmaf(y,y, z*z)));
      } else {
        t = make_float4(0.f, 0.f, 0.f, __builtin_inff());
      }
      sV[seg*512 + i] = t;
    }
    __syncthreads();
    #pragma unroll 4
    for (int k = 0; k < 64; ++k) {
      const float4 t = sV[seg*512 + k*8 + s];
      const int vi = v0 + k*8 + s;
      #pragma unroll
      for (int j = 0; j < 8; ++j) {
        const float dot = fmaf(px[j], t.x, fmaf(py[j], t.y, pz[j]*t.z));
        float d2 = fmaf(-2.f, dot, p2[j] + t.w);
        d2 = fmaxf(d2, 0.f);
        if (d2 < best[j]) { best[j] = d2; bidx[j] = vi; }
      }
    }
  }

  // in-wave 8-way reduce (lexicographic (d2, idx) min)
  #pragma unroll
  for (int off = 1; off <= 4; off <<= 1) {
    #pragma unroll
    for (int j = 0; j < 8; ++j) {
      const float ob = __shfl_xor(best[j], off, 64);
      const int   oi = __shfl_xor(bidx[j], off, 64);
      const bool take = (ob < best[j]) || ((ob == best[j]) && (oi < bidx[j]));
      if (take) { best[j] = ob; bidx[j] = oi; }
    }
  }
  float bb = best[0]; int bi = bidx[0];
  #pragma unroll
  for (int j = 1; j < 8; ++j) if (s == j) { bb = best[j]; bi = bidx[j]; }

  sRed[seg*256 + st] = ((ull_t)__float_as_uint(bb) << 32) | (uint_t)bi;
  __syncthreads();

  // ---- Phase B: features, 4 wave-uniform slices per point ----
  const int slice = seg, p = st;
  const int g = blockIdx.x * 256 + p;
  ull_t pv = sRed[p];
  #pragma unroll
  for (int q = 1; q < 4; ++q) { const ull_t o = sRed[q*256 + p]; if (o < pv) pv = o; }
  const int   wi = (int)(pv & 0xffffffffull);
  const float wd = __uint_as_float((uint_t)(pv >> 32));

  const float qx = pts[g*3+0], qy = pts[g*3+1], qz = pts[g*3+2];
  const float wgt = expf(-wd);
  const float sx = (cano[wi*3+0] - dmb[wi*3+0]) * wgt;
  const float sy = (cano[wi*3+1] - dmb[wi*3+1]) * wgt;
  const float sz = (cano[wi*3+2] - dmb[wi*3+2]) * wgt;

  if (slice == 0) {
    base3[g*3+0] = qx + sx; base3[g*3+1] = qy + sy; base3[g*3+2] = qz + sz;
    wsIp[0*(size_t)NPTS+g] = packsplit(qx);
    wsIp[1*(size_t)NPTS+g] = packsplit(qy);
    wsIp[2*(size_t)NPTS+g] = packsplit(qz);
    #pragma unroll
    for (int f = 0; f < 3; ++f) {
      const float F = (float)(1 << f);
      float s0,c0,s1,c1,s2,c2;
      sincosf(qx*F,&s0,&c0); sincosf(qy*F,&s1,&c1); sincosf(qz*F,&s2,&c2);
      const int k = 3 + 6*f;
      wsIp[(size_t)(k+0)*NPTS+g]=packsplit(s0); wsIp[(size_t)(k+1)*NPTS+g]=packsplit(s1);
      wsIp[(size_t)(k+2)*NPTS+g]=packsplit(s2); wsIp[(size_t)(k+3)*NPTS+g]=packsplit(c0);
      wsIp[(size_t)(k+4)*NPTS+g]=packsplit(c1); wsIp[(size_t)(k+5)*NPTS+g]=packsplit(c2);
    }
  } else if (slice == 1) {
    #pragma unroll
    for (int f = 3; f < 7; ++f) {
      const float F = (float)(1 << f);
      float s0,c0,s1,c1,s2,c2;
      sincosf(qx*F,&s0,&c0); sincosf(qy*F,&s1,&c1); sincosf(qz*F,&s2,&c2);
      const int k = 3 + 6*f;
      wsIp[(size_t)(k+0)*NPTS+g]=packsplit(s0); wsIp[(size_t)(k+1)*NPTS+g]=packsplit(s1);
      wsIp[(size_t)(k+2)*NPTS+g]=packsplit(s2); wsIp[(size_t)(k+3)*NPTS+g]=packsplit(c0);
      wsIp[(size_t)(k+4)*NPTS+g]=packsplit(c1); wsIp[(size_t)(k+5)*NPTS+g]=packsplit(c2);
    }
  } else if (slice == 2) {
    #pragma unroll
    for (int f = 7; f < 10; ++f) {
      const float F = (float)(1 << f);
      float s0,c0,s1,c1,s2,c2;
      sincosf(qx*F,&s0,&c0); sincosf(qy*F,&s1,&c1); sincosf(qz*F,&s2,&c2);
      const int k = 3 + 6*f;
      wsIp[(size_t)(k+0)*NPTS+g]=packsplit(s0); wsIp[(size_t)(k+1)*NPTS+g]=packsplit(s1);
      wsIp[(size_t)(k+2)*NPTS+g]=packsplit(s2); wsIp[(size_t)(k+3)*NPTS+g]=packsplit(c0);
      wsIp[(size_t)(k+4)*NPTS+g]=packsplit(c1); wsIp[(size_t)(k+5)*NPTS+g]=packsplit(c2);
    }
    #pragma unroll
    for (int j = 0; j < 16; ++j) wsIp[(size_t)(78+j)*NPTS + g] = packsplit(lat[g*LATD + j]);
  } else {
    wsIp[63*(size_t)NPTS+g]=packsplit(sx); wsIp[64*(size_t)NPTS+g]=packsplit(sy);
    wsIp[65*(size_t)NPTS+g]=packsplit(sz);
    #pragma unroll
    for (int f = 0; f < 2; ++f) {
      const float F = (float)(1 << f);
      float s0,c0,s1,c1,s2,c2;
      sincosf(sx*F,&s0,&c0); sincosf(sy*F,&s1,&c1); sincosf(sz*F,&s2,&c2);
      const int k = 66 + 6*f;
      wsIp[(size_t)(k+0)*NPTS+g]=packsplit(s0); wsIp[(size_t)(k+1)*NPTS+g]=packsplit(s1);
      wsIp[(size_t)(k+2)*NPTS+g]=packsplit(s2); wsIp[(size_t)(k+3)*NPTS+g]=packsplit(c0);
      wsIp[(size_t)(k+4)*NPTS+g]=packsplit(c1); wsIp[(size_t)(k+5)*NPTS+g]=packsplit(c2);
    }
    #pragma unroll
    for (int j = 16; j < 32; ++j) wsIp[(size_t)(78+j)*NPTS + g] = packsplit(lat[g*LATD + j]);
  }
}

// ------------- Kernel 2: fused MLP; W fragments read direct from global (L2) -------------
// M=128 pts/block, 512 threads = 8 waves (2x4), wave tile 64x32; 2 blocks/CU.

__device__ __forceinline__ void stage_X(ushort_t* __restrict__ sXh, ushort_t* __restrict__ sXl,
    const uint_t* __restrict__ wsIp, int g0, int tid)
{
  #pragma unroll
  for (int it = 0; it < 32; ++it) {
    const int idx = it*512 + tid;
    const int k = idx >> 7, m = idx & 127;
    uint_t u = 0;
    if (k < KF) u = wsIp[(size_t)k*NPTS + g0 + m];
    sXh[m*136 + k] = (ushort_t)(u & 0xffffu);
    sXl[m*136 + k] = (ushort_t)(u >> 16);
  }
}

__device__ __forceinline__ void zero_acc(f32x4 (&acc)[4][2]) {
  #pragma unroll
  for (int i = 0; i < 4; ++i)
    #pragma unroll
    for (int j = 0; j < 2; ++j)
      acc[i][j] = (f32x4){0.f,0.f,0.f,0.f};
}

__device__ __forceinline__ void mfma_panel_g(f32x4 (&acc)[4][2],
    const ushort_t* __restrict__ sXh, const ushort_t* __restrict__ sXl,
    const ushort_t* __restrict__ gWh, const ushort_t* __restrict__ gWl,
    int mq, int nq, int l15, int kq)
{
  #pragma unroll
  for (int ks = 0; ks < 4; ++ks) {
    const int ko = ks*32 + kq;
    bf16x8 bh[2], bl[2], ah[4], al[4];
    #pragma unroll
    for (int nt = 0; nt < 2; ++nt) {
      const int n = nq*32 + nt*16 + l15;
      bh[nt] = *(const bf16x8*)(gWh + n*128 + ko);
      bl[nt] = *(const bf16x8*)(gWl + n*128 + ko);
    }
    #pragma unroll
    for (int mt = 0; mt < 4; ++mt) {
      const int m = mq*64 + mt*16 + l15;
      ah[mt] = *(const bf16x8*)(sXh + m*136 + ko);
      al[mt] = *(const bf16x8*)(sXl + m*136 + ko);
    }
    #pragma unroll
    for (int mt = 0; mt < 4; ++mt)
      #pragma unroll
      for (int nt = 0; nt < 2; ++nt) {
        acc[mt][nt] = __builtin_amdgcn_mfma_f32_16x16x32_bf16(ah[mt], bh[nt], acc[mt][nt], 0,0,0);
        acc[mt][nt] = __builtin_amdgcn_mfma_f32_16x16x32_bf16(al[mt], bh[nt], acc[mt][nt], 0,0,0);
        acc[mt][nt] = __builtin_amdgcn_mfma_f32_16x16x32_bf16(ah[mt], bl[nt], acc[mt][nt], 0,0,0);
      }
  }
}

__device__ __forceinline__ void epi_relu_split(f32x4 (&acc)[4][2],
    ushort_t* __restrict__ sXh, ushort_t* __restrict__ sXl,
    const float* __restrict__ bias, int mq, int nq, int quad, int l15)
{
  #pragma unroll
  for (int mt = 0; mt < 4; ++mt)
    #pragma unroll
    for (int nt = 0; nt < 2; ++nt) {
      const int n = nq*32 + nt*16 + l15;
      const float bv = bias[n];
      #pragma unroll
      for (int r = 0; r < 4; ++r) {
        const int m = mq*64 + mt*16 + quad*4 + r;
        const float v = fmaxf(acc[mt][nt][r] + bv, 0.f);
        const ushort_t h = f2bf(v);
        sXh[m*136 + n] = h;
        sXl[m*136 + n] = f2bf(v - bf2f(h));
      }
    }
}

__global__ __launch_bounds__(512, 4) void k_mlp(
    const uint_t* __restrict__ wsIp, const float* __restrict__ base3,
    const ushort_t* __restrict__ wsWh, const ushort_t* __restrict__ wsWl,
    const float* __restrict__ b0, const float* __restrict__ b1,
    const float* __restrict__ b2, const float* __restrict__ b3,
    const float* __restrict__ b4, const float* __restrict__ b5,
    const float* __restrict__ b6, const float* __restrict__ b7,
    const float* __restrict__ w_out, const float* __restrict__ b_out,
    float* __restrict__ out)
{
  __shared__ __align__(16) char sMem[128*136*2*2];   // 69.6 KB: sXh|sXl; reused as sF
  __shared__ float sB[8*128 + 384 + 4];

  ushort_t* sXh = (ushort_t*)sMem;
  ushort_t* sXl = sXh + 128*136;

  const int tid  = threadIdx.x;
  const int lane = tid & 63, wid = tid >> 6;
  const int quad = lane >> 4, l15 = lane & 15, kq = quad*8;
  const int mq = wid & 1, nq = wid >> 1;
  const int g0 = blockIdx.x * 128;

  f32x4 acc[4][2];

  stage_X(sXh, sXl, wsIp, g0, tid);
  {
    const float* bs[8] = {b0,b1,b2,b3,b4,b5,b6,b7};
    if (tid < 128) {
      #pragma unroll
      for (int l = 0; l < 8; ++l) sB[l*128 + tid] = bs[l][tid];
    } else {
      sB[1024 + (tid - 128)] = w_out[tid - 128];
    }
    if (tid < 3) sB[1408 + tid] = b_out[tid];
  }
  __syncthreads();

  // L0
  zero_acc(acc);
  mfma_panel_g(acc, sXh, sXl, wsWh + 0, wsWl + 0, mq, nq, l15, kq);
  __syncthreads();
  epi_relu_split(acc, sXh, sXl, sB + 0, mq, nq, quad, l15);

  // L1..L3
  for (int l = 1; l <= 3; ++l) {
    __syncthreads();
    zero_acc(acc);
    mfma_panel_g(acc, sXh, sXl, wsWh + l*16384, wsWl + l*16384, mq, nq, l15, kq);
    __syncthreads();
    epi_relu_split(acc, sXh, sXl, sB + l*128, mq, nq, quad, l15);
  }

  // L4: x part first, then reload initial and accumulate
  __syncthreads();
  zero_acc(acc);
  mfma_panel_g(acc, sXh, sXl, wsWh + 81920, wsWl + 81920, mq, nq, l15, kq);
  __syncthreads();
  stage_X(sXh, sXl, wsIp, g0, tid);
  __syncthreads();
  mfma_panel_g(acc, sXh, sXl, wsWh + 65536, wsWl + 65536, mq, nq, l15, kq);
  __syncthreads();
  epi_relu_split(acc, sXh, sXl, sB + 4*128, mq, nq, quad, l15);

  // L5..L6
  for (int l = 5; l <= 6; ++l) {
    __syncthreads();
    zero_acc(acc);
    mfma_panel_g(acc, sXh, sXl, wsWh + 98304 + (l-5)*16384, wsWl + 98304 + (l-5)*16384, mq, nq, l15, kq);
    __syncthreads();
    epi_relu_split(acc, sXh, sXl, sB + l*128, mq, nq, quad, l15);
  }

  // L7: pre-activation = last_feat
  __syncthreads();
  zero_acc(acc);
  mfma_panel_g(acc, sXh, sXl, wsWh + 131072, wsWl + 131072, mq, nq, l15, kq);

  float* __restrict__ out1 = out + (size_t)NPTS*3;
  #pragma unroll
  for (int mt = 0; mt < 4; ++mt)
    #pragma unroll
    for (int nt = 0; nt < 2; ++nt) {
      const int n = nq*32 + nt*16 + l15;
      const float bv = sB[7*128 + n];
      #pragma unroll
      for (int r = 0; r < 4; ++r) {
        const int m = mq*64 + mt*16 + quad*4 + r;
        const float v = acc[mt][nt][r] + bv;
        out1[(size_t)(g0 + m)*128 + n] = v;
        acc[mt][nt][r] = fmaxf(v, 0.f);
      }
    }

  __syncthreads();                       // all sX reads done; overlay sF
  float* __restrict__ sF = (float*)sMem; // [128][132] fp32
  #pragma unroll
  for (int mt = 0; mt < 4; ++mt)
    #pragma unroll
    for (int nt = 0; nt < 2; ++nt) {
      const int n = nq*32 + nt*16 + l15;
      #pragma unroll
      for (int r = 0; r < 4; ++r) {
        const int m = mq*64 + mt*16 + quad*4 + r;
        sF[m*132 + n] = acc[mt][nt][r];
      }
    }
  __syncthreads();

  if (tid < 384) {
    const int m = tid / 3, c = tid - m*3;
    const float* __restrict__ xr = sF + m*132;
    const float* __restrict__ wc = sB + 1024 + c*128;
    float a = 0.f;
    #pragma unroll 8
    for (int k = 0; k < 128; ++k) a = fmaf(xr[k], wc[k], a);
    const int g = g0 + m;
    out[g*3 + c] = base3[g*3 + c] + a + sB[1408 + c];
  }
}

extern "C" void kernel_launch(void* const* d_in, const int* in_sizes, int n_in,
                              void* d_out, int out_size, void* d_ws, size_t ws_size,
                              hipStream_t stream)
{
  const float* pts  = (const float*)d_in[0];
  const float* dm   = (const float*)d_in[1];
  const float* cano = (const float*)d_in[2];
  const float* lat  = (const float*)d_in[3];
  const float* w[8]; const float* b[8];
  for (int i = 0; i < 8; ++i) {
    w[i] = (const float*)d_in[4 + 2*i];
    b[i] = (const float*)d_in[5 + 2*i];
  }
  const float* w_out = (const float*)d_in[20];
  const float* b_out = (const float*)d_in[21];
  float* out = (float*)d_out;

  // ws: wsIp [110][NPTS] uint (28.84MB) | base3 (786KB) | wsWh (288KB) | wsWl (288KB)
  uint_t*   wsIp  = (uint_t*)d_ws;
  float*    base3 = (float*)((char*)d_ws + (size_t)KF*NPTS*4);
  ushort_t* wsWh  = (ushort_t*)((char*)base3 + (size_t)NPTS*3*4);
  ushort_t* wsWl  = wsWh + 147456;

  k_nnfeat<<<256 + 8, 1024, 0, stream>>>(pts, dm, cano, lat,
      w[0],w[1],w[2],w[3],w[4],w[5],w[6],w[7], wsIp, base3, wsWh, wsWl);
  k_mlp<<<NPTS/128, 512, 0, stream>>>(wsIp, base3, wsWh, wsWl,
      b[0],b[1],b[2],b[3],b[4],b[5],b[6],b[7], w_out, b_out, out);
}

// Round 7
// 282.492 us; speedup vs baseline: 1.1636x; 1.0670x over previous
//
#include <hip/hip_runtime.h>
#include <math.h>

typedef unsigned short ushort_t;
typedef unsigned int   uint_t;
typedef unsigned long long ull_t;
typedef __attribute__((ext_vector_type(8)))  short bf16x8;
typedef __attribute__((ext_vector_type(16))) float f32x16;

#define NPTS   65536   // B*P
#define NV     5023
#define LATD   32
#define KF     110
#define FSTR   112     // feat row stride (uints)
#define SEGLEN 1256    // ceil(NV/4)

__device__ __forceinline__ ushort_t f2bf(float f) {
  union { float f; unsigned u; } x; x.f = f;
  unsigned r = x.u + 0x7fffu + ((x.u >> 16) & 1u);   // RNE
  return (ushort_t)(r >> 16);
}
__device__ __forceinline__ float bf2f(ushort_t u) {
  union { unsigned u; float f; } x; x.u = ((unsigned)u) << 16;
  return x.f;
}
__device__ __forceinline__ uint_t packsplit(float v) {
  const ushort_t h = f2bf(v);
  const ushort_t l = f2bf(v - bf2f(h));
  return (uint_t)h | ((uint_t)l << 16);
}

// dst weight panels (ushorts per plane), 9 panels of 16384 = [128n][128k]:
// p0:L0 p1:L1 p2:L2 p3:L3 p4:L4a(initial) p5:L4b(x) p6:L5 p7:L6 p8:L7

// ------------- Kernel 1: fused NN + m-major packed features + weight prep -------------
// 256 blocks x 1024 threads (4 segs x 256); prep distributed 576 elems/block.
__global__ __launch_bounds__(1024) void k_nnfeat(
    const float* __restrict__ pts, const float* __restrict__ dm,
    const float* __restrict__ cano, const float* __restrict__ lat,
    const float* __restrict__ w0, const float* __restrict__ w1,
    const float* __restrict__ w2, const float* __restrict__ w3,
    const float* __restrict__ w4, const float* __restrict__ w5,
    const float* __restrict__ w6, const float* __restrict__ w7,
    uint_t* __restrict__ feat, float* __restrict__ base3,
    ushort_t* __restrict__ wsWh, ushort_t* __restrict__ wsWl)
{
  const int tid = threadIdx.x;

  // ---- distributed weight prep: 576 elements per block ----
  if (tid < 576) {
    const int e = blockIdx.x * 576 + tid;
    const int p = e >> 14, local = e & 16383;
    const int n = local >> 7, k = local & 127;
    float v;
    if (p == 0)      v = (k < KF) ? w0[n*110 + k] : 0.f;
    else if (p == 1) v = w1[n*128 + k];
    else if (p == 2) v = w2[n*128 + k];
    else if (p == 3) v = w3[n*128 + k];
    else if (p == 4) v = (k < KF) ? w4[n*238 + k] : 0.f;
    else if (p == 5) v = w4[n*238 + KF + k];
    else if (p == 6) v = w5[n*128 + k];
    else if (p == 7) v = w6[n*128 + k];
    else             v = w7[n*128 + k];
    const ushort_t h = f2bf(v);
    wsWh[e] = h;
    wsWl[e] = f2bf(v - bf2f(h));
  }

  __shared__ float4 sV[4*512];     // 32 KB
  __shared__ ull_t  sRed[4*256];   // 8 KB

  const int seg = tid >> 8, st = tid & 255;
  const int s   = st & 7;
  const int pbase = blockIdx.x * 256 + (st >> 3) * 8;
  const int b   = blockIdx.x >> 7;
  const float* __restrict__ dmb = dm + b * NV * 3;
  const int v_lo = seg * SEGLEN;
  const int v_hi = (v_lo + SEGLEN < NV) ? v_lo + SEGLEN : NV;

  float px[8], py[8], pz[8], p2[8], best[8]; int bidx[8];
  #pragma unroll
  for (int j = 0; j < 8; ++j) {
    px[j] = pts[(pbase+j)*3+0]; py[j] = pts[(pbase+j)*3+1]; pz[j] = pts[(pbase+j)*3+2];
    p2[j] = fmaf(px[j],px[j], fmaf(py[j],py[j], pz[j]*pz[j]));
    best[j] = 3.4e38f; bidx[j] = 0;
  }

  #pragma unroll
  for (int c = 0; c < 3; ++c) {
    const int v0 = v_lo + c*512;
    __syncthreads();
    for (int i = st; i < 512; i += 256) {
      const int v = v0 + i;
      float4 t;
      if (v < v_hi) {
        const float x = dmb[v*3+0], y = dmb[v*3+1], z = dmb[v*3+2];
        t = make_float4(x, y, z, fmaf(x,x, fmaf(y,y, z*z)));
      } else {
        t = make_float4(0.f, 0.f, 0.f, __builtin_inff());
      }
      sV[seg*512 + i] = t;
    }
    __syncthreads();
    #pragma unroll 4
    for (int k = 0; k < 64; ++k) {
      const float4 t = sV[seg*512 + k*8 + s];
      const int vi = v0 + k*8 + s;
      #pragma unroll
      for (int j = 0; j < 8; ++j) {
        const float dot = fmaf(px[j], t.x, fmaf(py[j], t.y, pz[j]*t.z));
        float d2 = fmaf(-2.f, dot, p2[j] + t.w);
        d2 = fmaxf(d2, 0.f);
        if (d2 < best[j]) { best[j] = d2; bidx[j] = vi; }
      }
    }
  }

  #pragma unroll
  for (int off = 1; off <= 4; off <<= 1) {
    #pragma unroll
    for (int j = 0; j < 8; ++j) {
      const float ob = __shfl_xor(best[j], off, 64);
      const int   oi = __shfl_xor(bidx[j], off, 64);
      const bool take = (ob < best[j]) || ((ob == best[j]) && (oi < bidx[j]));
      if (take) { best[j] = ob; bidx[j] = oi; }
    }
  }
  float bb = best[0]; int bi = bidx[0];
  #pragma unroll
  for (int j = 1; j < 8; ++j) if (s == j) { bb = best[j]; bi = bidx[j]; }

  sRed[seg*256 + st] = ((ull_t)__float_as_uint(bb) << 32) | (uint_t)bi;
  __syncthreads();

  // ---- features, 4 wave-uniform slices per point, m-major feat[g][112] ----
  const int slice = seg, p = st;
  const int g = blockIdx.x * 256 + p;
  ull_t pv = sRed[p];
  #pragma unroll
  for (int q = 1; q < 4; ++q) { const ull_t o = sRed[q*256 + p]; if (o < pv) pv = o; }
  const int   wi = (int)(pv & 0xffffffffull);
  const float wd = __uint_as_float((uint_t)(pv >> 32));

  const float qx = pts[g*3+0], qy = pts[g*3+1], qz = pts[g*3+2];
  const float wgt = expf(-wd);
  const float sx = (cano[wi*3+0] - dmb[wi*3+0]) * wgt;
  const float sy = (cano[wi*3+1] - dmb[wi*3+1]) * wgt;
  const float sz = (cano[wi*3+2] - dmb[wi*3+2]) * wgt;

  uint_t* __restrict__ fr = feat + (size_t)g * FSTR;

  if (slice == 0) {
    base3[g*3+0] = qx + sx; base3[g*3+1] = qy + sy; base3[g*3+2] = qz + sz;
    fr[0] = packsplit(qx); fr[1] = packsplit(qy); fr[2] = packsplit(qz);
    #pragma unroll
    for (int f = 0; f < 3; ++f) {
      const float F = (float)(1 << f);
      float s0,c0,s1,c1,s2,c2;
      sincosf(qx*F,&s0,&c0); sincosf(qy*F,&s1,&c1); sincosf(qz*F,&s2,&c2);
      const int k = 3 + 6*f;
      fr[k+0]=packsplit(s0); fr[k+1]=packsplit(s1); fr[k+2]=packsplit(s2);
      fr[k+3]=packsplit(c0); fr[k+4]=packsplit(c1); fr[k+5]=packsplit(c2);
    }
    fr[110] = 0; fr[111] = 0;          // pad
  } else if (slice == 1) {
    #pragma unroll
    for (int f = 3; f < 7; ++f) {
      const float F = (float)(1 << f);
      float s0,c0,s1,c1,s2,c2;
      sincosf(qx*F,&s0,&c0); sincosf(qy*F,&s1,&c1); sincosf(qz*F,&s2,&c2);
      const int k = 3 + 6*f;
      fr[k+0]=packsplit(s0); fr[k+1]=packsplit(s1); fr[k+2]=packsplit(s2);
      fr[k+3]=packsplit(c0); fr[k+4]=packsplit(c1); fr[k+5]=packsplit(c2);
    }
  } else if (slice == 2) {
    #pragma unroll
    for (int f = 7; f < 10; ++f) {
      const float F = (float)(1 << f);
      float s0,c0,s1,c1,s2,c2;
      sincosf(qx*F,&s0,&c0); sincosf(qy*F,&s1,&c1); sincosf(qz*F,&s2,&c2);
      const int k = 3 + 6*f;
      fr[k+0]=packsplit(s0); fr[k+1]=packsplit(s1); fr[k+2]=packsplit(s2);
      fr[k+3]=packsplit(c0); fr[k+4]=packsplit(c1); fr[k+5]=packsplit(c2);
    }
    #pragma unroll
    for (int j = 0; j < 16; ++j) fr[78+j] = packsplit(lat[g*LATD + j]);
  } else {
    fr[63]=packsplit(sx); fr[64]=packsplit(sy); fr[65]=packsplit(sz);
    #pragma unroll
    for (int f = 0; f < 2; ++f) {
      const float F = (float)(1 << f);
      float s0,c0,s1,c1,s2,c2;
      sincosf(sx*F,&s0,&c0); sincosf(sy*F,&s1,&c1); sincosf(sz*F,&s2,&c2);
      const int k = 66 + 6*f;
      fr[k+0]=packsplit(s0); fr[k+1]=packsplit(s1); fr[k+2]=packsplit(s2);
      fr[k+3]=packsplit(c0); fr[k+4]=packsplit(c1); fr[k+5]=packsplit(c2);
    }
    #pragma unroll
    for (int j = 16; j < 32; ++j) fr[78+j] = packsplit(lat[g*LATD + j]);
  }
}

// ------------- Kernel 2: fused MLP, 32x32x16 MFMA, B direct from global -------------
// M=128/block, 256 threads = 4 waves (2x2), wave tile 64x64; LDS 75.3KB -> 2 blk/CU.

__device__ __forceinline__ void stage_X(ushort_t* __restrict__ sXh, ushort_t* __restrict__ sXl,
    const uint_t* __restrict__ feat, int g0, int tid)
{
  #pragma unroll
  for (int it = 0; it < 14; ++it) {
    const int idx = it*256 + tid;          // 0..3583
    const int m = idx / 28, kc = idx - m*28;
    const uint4 u = *(const uint4*)(feat + (size_t)(g0 + m)*FSTR + kc*4);
    uint2 h, l;
    h.x = (u.x & 0xffffu) | (u.y << 16);
    h.y = (u.z & 0xffffu) | (u.w << 16);
    l.x = (u.x >> 16) | (u.y & 0xffff0000u);
    l.y = (u.z >> 16) | (u.w & 0xffff0000u);
    *(uint2*)(sXh + m*136 + kc*4) = h;
    *(uint2*)(sXl + m*136 + kc*4) = l;
  }
  { // zero pad k=112..127
    const int m = tid >> 1, h = tid & 1;
    const uint4 z = {0,0,0,0};
    *(uint4*)(sXh + m*136 + 112 + h*8) = z;
    *(uint4*)(sXl + m*136 + 112 + h*8) = z;
  }
}

__device__ __forceinline__ void zero_acc(f32x16 (&acc)[2][2]) {
  #pragma unroll
  for (int i = 0; i < 2; ++i)
    #pragma unroll
    for (int j = 0; j < 2; ++j)
      acc[i][j] = (f32x16)(0.f);
}

// A,B layout (32x32x16): row/col = lane&31, k = (lane>>5)*8 + j
__device__ __forceinline__ void mfma_panel(f32x16 (&acc)[2][2],
    const ushort_t* __restrict__ sXh, const ushort_t* __restrict__ sXl,
    const ushort_t* __restrict__ gWh, const ushort_t* __restrict__ gWl,
    int mq, int nq, int l31, int kh)
{
  #pragma unroll
  for (int ks = 0; ks < 8; ++ks) {
    const int ko = ks*16 + kh;
    bf16x8 ah[2], al[2], bh[2], bl[2];
    #pragma unroll
    for (int tn = 0; tn < 2; ++tn) {
      const int n = nq*64 + tn*32 + l31;
      bh[tn] = *(const bf16x8*)(gWh + n*128 + ko);
      bl[tn] = *(const bf16x8*)(gWl + n*128 + ko);
    }
    #pragma unroll
    for (int tm = 0; tm < 2; ++tm) {
      const int m = mq*64 + tm*32 + l31;
      ah[tm] = *(const bf16x8*)(sXh + m*136 + ko);
      al[tm] = *(const bf16x8*)(sXl + m*136 + ko);
    }
    #pragma unroll
    for (int tm = 0; tm < 2; ++tm)
      #pragma unroll
      for (int tn = 0; tn < 2; ++tn) {
        acc[tm][tn] = __builtin_amdgcn_mfma_f32_32x32x16_bf16(ah[tm], bh[tn], acc[tm][tn], 0,0,0);
        acc[tm][tn] = __builtin_amdgcn_mfma_f32_32x32x16_bf16(al[tm], bh[tn], acc[tm][tn], 0,0,0);
        acc[tm][tn] = __builtin_amdgcn_mfma_f32_32x32x16_bf16(ah[tm], bl[tn], acc[tm][tn], 0,0,0);
      }
  }
}

// C/D layout (32x32): col=lane&31, row=(r&3)+8*(r>>2)+4*(lane>>5)  [m74/m101 verified]
__device__ __forceinline__ void epi_relu_split(f32x16 (&acc)[2][2],
    ushort_t* __restrict__ sXh, ushort_t* __restrict__ sXl,
    const float* __restrict__ bias, int mq, int nq, int l31, int lh)
{
  #pragma unroll
  for (int tm = 0; tm < 2; ++tm)
    #pragma unroll
    for (int tn = 0; tn < 2; ++tn) {
      const int n = nq*64 + tn*32 + l31;
      const float bv = bias[n];
      #pragma unroll
      for (int r = 0; r < 16; ++r) {
        const int row = (r & 3) + 8*(r >> 2) + 4*lh;
        const int m = mq*64 + tm*32 + row;
        const float v = fmaxf(acc[tm][tn][r] + bv, 0.f);
        const ushort_t h = f2bf(v);
        sXh[m*136 + n] = h;
        sXl[m*136 + n] = f2bf(v - bf2f(h));
      }
    }
}

__global__ __launch_bounds__(256, 2) void k_mlp(
    const uint_t* __restrict__ feat, const float* __restrict__ base3,
    const ushort_t* __restrict__ wsWh, const ushort_t* __restrict__ wsWl,
    const float* __restrict__ b0, const float* __restrict__ b1,
    const float* __restrict__ b2, const float* __restrict__ b3,
    const float* __restrict__ b4, const float* __restrict__ b5,
    const float* __restrict__ b6, const float* __restrict__ b7,
    const float* __restrict__ w_out, const float* __restrict__ b_out,
    float* __restrict__ out)
{
  __shared__ __align__(16) char sMem[128*136*2*2];   // 69.6 KB: sXh|sXl, reused as sF
  __shared__ float sB[8*128 + 384 + 4];

  ushort_t* sXh = (ushort_t*)sMem;
  ushort_t* sXl = sXh + 128*136;

  const int tid  = threadIdx.x;
  const int lane = tid & 63, wid = tid >> 6;
  const int l31 = lane & 31, lh = lane >> 5, kh = lh*8;
  const int mq = wid & 1, nq = wid >> 1;
  const int g0 = blockIdx.x * 128;

  f32x16 acc[2][2];

  stage_X(sXh, sXl, feat, g0, tid);
  {
    const float* bs[8] = {b0,b1,b2,b3,b4,b5,b6,b7};
    if (tid < 128) {
      #pragma unroll
      for (int l = 0; l < 8; ++l) sB[l*128 + tid] = bs[l][tid];
    }
    for (int i = tid; i < 384; i += 256) sB[1024 + i] = w_out[i];
    if (tid < 3) sB[1408 + tid] = b_out[tid];
  }
  __syncthreads();

  // L0 (panel 0)
  zero_acc(acc);
  mfma_panel(acc, sXh, sXl, wsWh + 0, wsWl + 0, mq, nq, l31, kh);
  __syncthreads();
  epi_relu_split(acc, sXh, sXl, sB + 0, mq, nq, l31, lh);

  // L1..L3 (panels 1..3)
  for (int l = 1; l <= 3; ++l) {
    __syncthreads();
    zero_acc(acc);
    mfma_panel(acc, sXh, sXl, wsWh + l*16384, wsWl + l*16384, mq, nq, l31, kh);
    __syncthreads();
    epi_relu_split(acc, sXh, sXl, sB + l*128, mq, nq, l31, lh);
  }

  // L4: x part (panel 5), then reload initial, accumulate initial part (panel 4)
  __syncthreads();
  zero_acc(acc);
  mfma_panel(acc, sXh, sXl, wsWh + 5*16384, wsWl + 5*16384, mq, nq, l31, kh);
  __syncthreads();
  stage_X(sXh, sXl, feat, g0, tid);
  __syncthreads();
  mfma_panel(acc, sXh, sXl, wsWh + 4*16384, wsWl + 4*16384, mq, nq, l31, kh);
  __syncthreads();
  epi_relu_split(acc, sXh, sXl, sB + 4*128, mq, nq, l31, lh);

  // L5..L6 (panels 6..7)
  for (int l = 5; l <= 6; ++l) {
    __syncthreads();
    zero_acc(acc);
    mfma_panel(acc, sXh, sXl, wsWh + (l+1)*16384, wsWl + (l+1)*16384, mq, nq, l31, kh);
    __syncthreads();
    epi_relu_split(acc, sXh, sXl, sB + l*128, mq, nq, l31, lh);
  }

  // L7 (panel 8): pre-activation = last_feat
  __syncthreads();
  zero_acc(acc);
  mfma_panel(acc, sXh, sXl, wsWh + 8*16384, wsWl + 8*16384, mq, nq, l31, kh);

  float* __restrict__ out1 = out + (size_t)NPTS*3;
  #pragma unroll
  for (int tm = 0; tm < 2; ++tm)
    #pragma unroll
    for (int tn = 0; tn < 2; ++tn) {
      const int n = nq*64 + tn*32 + l31;
      const float bv = sB[7*128 + n];
      #pragma unroll
      for (int r = 0; r < 16; ++r) {
        const int row = (r & 3) + 8*(r >> 2) + 4*lh;
        const int m = mq*64 + tm*32 + row;
        const float v = acc[tm][tn][r] + bv;
        out1[(size_t)(g0 + m)*128 + n] = v;
        acc[tm][tn][r] = fmaxf(v, 0.f);
      }
    }

  __syncthreads();                       // all sX reads done; overlay sF
  float* __restrict__ sF = (float*)sMem; // [128][132] fp32
  #pragma unroll
  for (int tm = 0; tm < 2; ++tm)
    #pragma unroll
    for (int tn = 0; tn < 2; ++tn) {
      const int n = nq*64 + tn*32 + l31;
      #pragma unroll
      for (int r = 0; r < 16; ++r) {
        const int row = (r & 3) + 8*(r >> 2) + 4*lh;
        const int m = mq*64 + tm*32 + row;
        sF[m*132 + n] = acc[tm][tn][r];
      }
    }
  __syncthreads();

  for (int pair = tid; pair < 384; pair += 256) {
    const int m = pair / 3, c = pair - m*3;
    const float* __restrict__ xr = sF + m*132;
    const float* __restrict__ wc = sB + 1024 + c*128;
    float a = 0.f;
    #pragma unroll 8
    for (int k = 0; k < 128; ++k) a = fmaf(xr[k], wc[k], a);
    const int g = g0 + m;
    out[g*3 + c] = base3[g*3 + c] + a + sB[1408 + c];
  }
}

extern "C" void kernel_launch(void* const* d_in, const int* in_sizes, int n_in,
                              void* d_out, int out_size, void* d_ws, size_t ws_size,
                              hipStream_t stream)
{
  const float* pts  = (const float*)d_in[0];
  const float* dm   = (const float*)d_in[1];
  const float* cano = (const float*)d_in[2];
  const float* lat  = (const float*)d_in[3];
  const float* w[8]; const float* b[8];
  for (int i = 0; i < 8; ++i) {
    w[i] = (const float*)d_in[4 + 2*i];
    b[i] = (const float*)d_in[5 + 2*i];
  }
  const float* w_out = (const float*)d_in[20];
  const float* b_out = (const float*)d_in[21];
  float* out = (float*)d_out;

  // ws: feat [NPTS][112] uint (29.36MB) | base3 (786KB) | wsWh (288KB) | wsWl (288KB)
  uint_t*   feat  = (uint_t*)d_ws;
  float*    base3 = (float*)((char*)d_ws + (size_t)NPTS*FSTR*4);
  ushort_t* wsWh  = (ushort_t*)((char*)base3 + (size_t)NPTS*3*4);
  ushort_t* wsWl  = wsWh + 147456;

  k_nnfeat<<<256, 1024, 0, stream>>>(pts, dm, cano, lat,
      w[0],w[1],w[2],w[3],w[4],w[5],w[6],w[7], feat, base3, wsWh, wsWl);
  k_mlp<<<NPTS/128, 256, 0, stream>>>(feat, base3, wsWh, wsWl,
      b[0],b[1],b[2],b[3],b[4],b[5],b[6],b[7], w_out, b_out, out);
}

// Round 9
// 273.860 us; speedup vs baseline: 1.2003x; 1.0315x over previous
//
#include <hip/hip_runtime.h>
#include <math.h>

typedef unsigned short ushort_t;
typedef unsigned int   uint_t;
typedef __attribute__((ext_vector_type(8)))  short bf16x8;
typedef __attribute__((ext_vector_type(16))) float f32x16;

#define NPTS   65536   // B*P
#define NV     5023
#define LATD   32
#define KF     110
#define FSTR   112     // feat row stride (uints)

__device__ __forceinline__ ushort_t f2bf(float f) {
  union { float f; unsigned u; } x; x.f = f;
  unsigned r = x.u + 0x7fffu + ((x.u >> 16) & 1u);   // RNE
  return (ushort_t)(r >> 16);
}
__device__ __forceinline__ float bf2f(ushort_t u) {
  union { unsigned u; float f; } x; x.u = ((unsigned)u) << 16;
  return x.f;
}
__device__ __forceinline__ uint_t packsplit(float v) {
  const ushort_t h = f2bf(v);
  const ushort_t l = f2bf(v - bf2f(h));
  return (uint_t)h | ((uint_t)l << 16);
}

// weight panels (ushorts/plane), 9 x 16384 = [128n][128k]:
// p0:L0 p1:L1 p2:L2 p3:L3 p4:L4a(initial) p5:L4b(x) p6:L5 p7:L6 p8:L7

// ------------- Kernel 1: NN (4 pts/lane x 16-way split) + features + weight prep -------------
// 1024 blocks x 256 threads; 64 points/block; each wave covers full NV for its 16 pts.
// NOTE: per-pair metric MUST be d2 = fmaf(-2*dot, p2 + v2) with clamp — matches
// reference rounding (r7-verified). The sc = v2-2dot variant flips argmin (r8 failure).
__global__ __launch_bounds__(256, 4) void k_nnfeat(
    const float* __restrict__ pts, const float* __restrict__ dm,
    const float* __restrict__ cano, const float* __restrict__ lat,
    const float* __restrict__ w0, const float* __restrict__ w1,
    const float* __restrict__ w2, const float* __restrict__ w3,
    const float* __restrict__ w4, const float* __restrict__ w5,
    const float* __restrict__ w6, const float* __restrict__ w7,
    uint_t* __restrict__ feat, float* __restrict__ base3,
    ushort_t* __restrict__ wsWh, ushort_t* __restrict__ wsWl)
{
  const int tid = threadIdx.x;

  // distributed weight prep: 144 elements per block (1024*144 = 147456)
  if (tid < 144) {
    const int e = blockIdx.x * 144 + tid;
    const int p = e >> 14, local = e & 16383;
    const int n = local >> 7, k = local & 127;
    float v;
    if (p == 0)      v = (k < KF) ? w0[n*110 + k] : 0.f;
    else if (p == 1) v = w1[n*128 + k];
    else if (p == 2) v = w2[n*128 + k];
    else if (p == 3) v = w3[n*128 + k];
    else if (p == 4) v = (k < KF) ? w4[n*238 + k] : 0.f;
    else if (p == 5) v = w4[n*238 + KF + k];
    else if (p == 6) v = w5[n*128 + k];
    else if (p == 7) v = w6[n*128 + k];
    else             v = w7[n*128 + k];
    const ushort_t h = f2bf(v);
    wsWh[e] = h;
    wsWl[e] = f2bf(v - bf2f(h));
  }

  __shared__ float4 sV[512];    // 8 KB vertex chunk
  __shared__ float  sD[64];
  __shared__ int    sI[64];

  const int lane = tid & 63, w = tid >> 6;
  const int slot = lane >> 4, s = lane & 15;
  const int g0 = blockIdx.x * 64;
  const int b  = blockIdx.x >> 9;               // 512 blocks per batch
  const float* __restrict__ dmb = dm + b * NV * 3;
  const int pbase = g0 + w*16 + slot*4;

  float px[4], py[4], pz[4], p2[4], bs[4]; int bi[4];
  #pragma unroll
  for (int j = 0; j < 4; ++j) {
    px[j] = pts[(pbase+j)*3+0]; py[j] = pts[(pbase+j)*3+1]; pz[j] = pts[(pbase+j)*3+2];
    p2[j] = fmaf(px[j],px[j], fmaf(py[j],py[j], pz[j]*pz[j]));
    bs[j] = 3.4e38f; bi[j] = 0;
  }

  for (int v0 = 0; v0 < NV; v0 += 512) {        // 10 chunks
    __syncthreads();
    #pragma unroll
    for (int it = 0; it < 2; ++it) {
      const int i = it*256 + tid;
      const int v = v0 + i;
      float4 t;
      if (v < NV) {
        const float x = dmb[v*3+0], y = dmb[v*3+1], z = dmb[v*3+2];
        t = make_float4(x, y, z, fmaf(x,x, fmaf(y,y, z*z)));
      } else {
        t = make_float4(0.f, 0.f, 0.f, __builtin_inff());
      }
      sV[i] = t;
    }
    __syncthreads();
    #pragma unroll 8
    for (int k = 0; k < 32; ++k) {
      const float4 t = sV[k*16 + s];
      const int vi = v0 + k*16 + s;
      #pragma unroll
      for (int j = 0; j < 4; ++j) {
        const float dot = fmaf(px[j], t.x, fmaf(py[j], t.y, pz[j]*t.z));
        float d2 = fmaf(-2.f, dot, p2[j] + t.w);      // ref formula, r7-verified
        d2 = fmaxf(d2, 0.f);
        if (d2 < bs[j]) { bs[j] = d2; bi[j] = vi; }   // strict < => first index
      }
    }
  }

  // reduce over 16 splits (butterfly, lexicographic (d2, idx) min)
  #pragma unroll
  for (int off = 1; off <= 8; off <<= 1) {
    #pragma unroll
    for (int j = 0; j < 4; ++j) {
      const float ob = __shfl_xor(bs[j], off, 64);
      const int   oi = __shfl_xor(bi[j], off, 64);
      const bool take = (ob < bs[j]) || ((ob == bs[j]) && (oi < bi[j]));
      if (take) { bs[j] = ob; bi[j] = oi; }
    }
  }
  if (s == 0) {
    #pragma unroll
    for (int j = 0; j < 4; ++j) {
      sD[w*16 + slot*4 + j] = bs[j];
      sI[w*16 + slot*4 + j] = bi[j];
    }
  }
  __syncthreads();

  // ---- features: 4 wave-uniform slices per point ----
  const int p = tid & 63, slice = tid >> 6;
  const int g = g0 + p;
  const float wd = sD[p];
  const int   wi = sI[p];

  const float qx = pts[g*3+0], qy = pts[g*3+1], qz = pts[g*3+2];
  const float wgt = expf(-wd);
  const float sx = (cano[wi*3+0] - dmb[wi*3+0]) * wgt;
  const float sy = (cano[wi*3+1] - dmb[wi*3+1]) * wgt;
  const float sz = (cano[wi*3+2] - dmb[wi*3+2]) * wgt;

  uint_t* __restrict__ fr = feat + (size_t)g * FSTR;

  if (slice == 0) {
    base3[g*3+0] = qx + sx; base3[g*3+1] = qy + sy; base3[g*3+2] = qz + sz;
    fr[0] = packsplit(qx); fr[1] = packsplit(qy); fr[2] = packsplit(qz);
    #pragma unroll
    for (int f = 0; f < 3; ++f) {
      const float F = (float)(1 << f);
      float s0,c0,s1,c1,s2,c2;
      sincosf(qx*F,&s0,&c0); sincosf(qy*F,&s1,&c1); sincosf(qz*F,&s2,&c2);
      const int k = 3 + 6*f;
      fr[k+0]=packsplit(s0); fr[k+1]=packsplit(s1); fr[k+2]=packsplit(s2);
      fr[k+3]=packsplit(c0); fr[k+4]=packsplit(c1); fr[k+5]=packsplit(c2);
    }
    fr[110] = 0; fr[111] = 0;
  } else if (slice == 1) {
    #pragma unroll
    for (int f = 3; f < 7; ++f) {
      const float F = (float)(1 << f);
      float s0,c0,s1,c1,s2,c2;
      sincosf(qx*F,&s0,&c0); sincosf(qy*F,&s1,&c1); sincosf(qz*F,&s2,&c2);
      const int k = 3 + 6*f;
      fr[k+0]=packsplit(s0); fr[k+1]=packsplit(s1); fr[k+2]=packsplit(s2);
      fr[k+3]=packsplit(c0); fr[k+4]=packsplit(c1); fr[k+5]=packsplit(c2);
    }
  } else if (slice == 2) {
    #pragma unroll
    for (int f = 7; f < 10; ++f) {
      const float F = (float)(1 << f);
      float s0,c0,s1,c1,s2,c2;
      sincosf(qx*F,&s0,&c0); sincosf(qy*F,&s1,&c1); sincosf(qz*F,&s2,&c2);
      const int k = 3 + 6*f;
      fr[k+0]=packsplit(s0); fr[k+1]=packsplit(s1); fr[k+2]=packsplit(s2);
      fr[k+3]=packsplit(c0); fr[k+4]=packsplit(c1); fr[k+5]=packsplit(c2);
    }
    #pragma unroll
    for (int j = 0; j < 16; ++j) fr[78+j] = packsplit(lat[g*LATD + j]);
  } else {
    fr[63]=packsplit(sx); fr[64]=packsplit(sy); fr[65]=packsplit(sz);
    #pragma unroll
    for (int f = 0; f < 2; ++f) {
      const float F = (float)(1 << f);
      float s0,c0,s1,c1,s2,c2;
      sincosf(sx*F,&s0,&c0); sincosf(sy*F,&s1,&c1); sincosf(sz*F,&s2,&c2);
      const int k = 66 + 6*f;
      fr[k+0]=packsplit(s0); fr[k+1]=packsplit(s1); fr[k+2]=packsplit(s2);
      fr[k+3]=packsplit(c0); fr[k+4]=packsplit(c1); fr[k+5]=packsplit(c2);
    }
    #pragma unroll
    for (int j = 16; j < 32; ++j) fr[78+j] = packsplit(lat[g*LATD + j]);
  }
}

// ------------- Kernel 2: fused MLP, 32x32x16 MFMA, interleaved hi|lo LDS, global B -------------
// M=128/block, 256 threads = 4 waves (2x2), wave tile 64x64; LDS 75.3 KB -> 2 blk/CU.

__device__ __forceinline__ void stage_X(uint_t* __restrict__ sX,
    const uint_t* __restrict__ feat, int g0, int tid)
{
  #pragma unroll
  for (int it = 0; it < 14; ++it) {
    const int idx = it*256 + tid;              // 0..3583 = 128 x 28
    const int m = idx / 28, kc = idx - m*28;
    *(uint4*)(sX + m*136 + kc*4) = *(const uint4*)(feat + (size_t)(g0 + m)*FSTR + kc*4);
  }
  const uint4 z = {0,0,0,0};
  #pragma unroll
  for (int it = 0; it < 2; ++it) {
    const int idx = it*256 + tid;              // 0..511 = 128 x 4
    const int m = idx >> 2, q = idx & 3;
    *(uint4*)(sX + m*136 + 112 + q*4) = z;
  }
}

__device__ __forceinline__ void zero_acc(f32x16 (&acc)[2][2]) {
  #pragma unroll
  for (int i = 0; i < 2; ++i)
    #pragma unroll
    for (int j = 0; j < 2; ++j)
      acc[i][j] = (f32x16)(0.f);
}

// A,B layout (32x32x16): row/col = lane&31, k = (lane>>5)*8 + j
__device__ __forceinline__ void mfma_panel(f32x16 (&acc)[2][2],
    const uint_t* __restrict__ sX,
    const ushort_t* __restrict__ gWh, const ushort_t* __restrict__ gWl,
    int mq, int nq, int l31, int lh)
{
  const int kh = lh*8;
  bf16x8 bh[2], bl[2], nbh[2], nbl[2];
  #pragma unroll
  for (int tn = 0; tn < 2; ++tn) {
    const int n = nq*64 + tn*32 + l31;
    bh[tn] = *(const bf16x8*)(gWh + n*128 + kh);
    bl[tn] = *(const bf16x8*)(gWl + n*128 + kh);
  }
  #pragma unroll
  for (int ks = 0; ks < 8; ++ks) {
    const int ko = ks*16 + kh;
    if (ks < 7) {     // prefetch next-ks B frags
      #pragma unroll
      for (int tn = 0; tn < 2; ++tn) {
        const int n = nq*64 + tn*32 + l31;
        nbh[tn] = *(const bf16x8*)(gWh + n*128 + ko + 16);
        nbl[tn] = *(const bf16x8*)(gWl + n*128 + ko + 16);
      }
    }
    bf16x8 ah[2], al[2];
    #pragma unroll
    for (int tm = 0; tm < 2; ++tm) {
      const int m = mq*64 + tm*32 + l31;
      const uint4 ua = *(const uint4*)(sX + m*136 + ko);
      const uint4 ub = *(const uint4*)(sX + m*136 + ko + 4);
      union { uint_t u[4]; bf16x8 v; } H, L;
      H.u[0] = (ua.x & 0xffffu) | (ua.y << 16);
      H.u[1] = (ua.z & 0xffffu) | (ua.w << 16);
      H.u[2] = (ub.x & 0xffffu) | (ub.y << 16);
      H.u[3] = (ub.z & 0xffffu) | (ub.w << 16);
      L.u[0] = (ua.x >> 16) | (ua.y & 0xffff0000u);
      L.u[1] = (ua.z >> 16) | (ua.w & 0xffff0000u);
      L.u[2] = (ub.x >> 16) | (ub.y & 0xffff0000u);
      L.u[3] = (ub.z >> 16) | (ub.w & 0xffff0000u);
      ah[tm] = H.v; al[tm] = L.v;
    }
    #pragma unroll
    for (int tm = 0; tm < 2; ++tm)
      #pragma unroll
      for (int tn = 0; tn < 2; ++tn) {
        acc[tm][tn] = __builtin_amdgcn_mfma_f32_32x32x16_bf16(ah[tm], bh[tn], acc[tm][tn], 0,0,0);
        acc[tm][tn] = __builtin_amdgcn_mfma_f32_32x32x16_bf16(al[tm], bh[tn], acc[tm][tn], 0,0,0);
        acc[tm][tn] = __builtin_amdgcn_mfma_f32_32x32x16_bf16(ah[tm], bl[tn], acc[tm][tn], 0,0,0);
      }
    if (ks < 7) {
      #pragma unroll
      for (int tn = 0; tn < 2; ++tn) { bh[tn] = nbh[tn]; bl[tn] = nbl[tn]; }
    }
  }
}

// C/D layout (32x32): col=lane&31, row=(r&3)+8*(r>>2)+4*(lane>>5)
__device__ __forceinline__ void epi_relu(f32x16 (&acc)[2][2], uint_t* __restrict__ sX,
    const float* __restrict__ bias, int mq, int nq, int l31, int lh)
{
  #pragma unroll
  for (int tm = 0; tm < 2; ++tm)
    #pragma unroll
    for (int tn = 0; tn < 2; ++tn) {
      const int n = nq*64 + tn*32 + l31;
      const float bv = bias[n];
      #pragma unroll
      for (int r = 0; r < 16; ++r) {
        const int row = (r & 3) + 8*(r >> 2) + 4*lh;
        const int m = mq*64 + tm*32 + row;
        const float v = fmaxf(acc[tm][tn][r] + bv, 0.f);
        const ushort_t h = f2bf(v);
        const ushort_t l = f2bf(v - bf2f(h));
        sX[m*136 + n] = (uint_t)h | ((uint_t)l << 16);   // b32, conflict-free
      }
    }
}

__global__ __launch_bounds__(256, 2) void k_mlp(
    const uint_t* __restrict__ feat, const float* __restrict__ base3,
    const ushort_t* __restrict__ wsWh, const ushort_t* __restrict__ wsWl,
    const float* __restrict__ b0, const float* __restrict__ b1,
    const float* __restrict__ b2, const float* __restrict__ b3,
    const float* __restrict__ b4, const float* __restrict__ b5,
    const float* __restrict__ b6, const float* __restrict__ b7,
    const float* __restrict__ w_out, const float* __restrict__ b_out,
    float* __restrict__ out)
{
  __shared__ __align__(16) uint_t sX[128*136];   // 69.6 KB (h|l<<16); reused as sF
  __shared__ float sB[8*128 + 384 + 4];

  const int tid  = threadIdx.x;
  const int lane = tid & 63, wid = tid >> 6;
  const int l31 = lane & 31, lh = lane >> 5;
  const int mq = wid & 1, nq = wid >> 1;
  const int g0 = blockIdx.x * 128;

  f32x16 acc[2][2];

  stage_X(sX, feat, g0, tid);
  {
    const float* bs[8] = {b0,b1,b2,b3,b4,b5,b6,b7};
    if (tid < 128) {
      #pragma unroll
      for (int l = 0; l < 8; ++l) sB[l*128 + tid] = bs[l][tid];
    }
    for (int i = tid; i < 384; i += 256) sB[1024 + i] = w_out[i];
    if (tid < 3) sB[1408 + tid] = b_out[tid];
  }
  __syncthreads();

  // L0 (panel 0)
  zero_acc(acc);
  mfma_panel(acc, sX, wsWh + 0, wsWl + 0, mq, nq, l31, lh);
  __syncthreads();
  epi_relu(acc, sX, sB + 0, mq, nq, l31, lh);

  // L1..L3 (panels 1..3)
  for (int l = 1; l <= 3; ++l) {
    __syncthreads();
    zero_acc(acc);
    mfma_panel(acc, sX, wsWh + l*16384, wsWl + l*16384, mq, nq, l31, lh);
    __syncthreads();
    epi_relu(acc, sX, sB + l*128, mq, nq, l31, lh);
  }

  // L4: x part (panel 5), then reload initial, accumulate initial part (panel 4)
  __syncthreads();
  zero_acc(acc);
  mfma_panel(acc, sX, wsWh + 5*16384, wsWl + 5*16384, mq, nq, l31, lh);
  __syncthreads();
  stage_X(sX, feat, g0, tid);
  __syncthreads();
  mfma_panel(acc, sX, wsWh + 4*16384, wsWl + 4*16384, mq, nq, l31, lh);
  __syncthreads();
  epi_relu(acc, sX, sB + 4*128, mq, nq, l31, lh);

  // L5..L6 (panels 6..7)
  for (int l = 5; l <= 6; ++l) {
    __syncthreads();
    zero_acc(acc);
    mfma_panel(acc, sX, wsWh + (l+1)*16384, wsWl + (l+1)*16384, mq, nq, l31, lh);
    __syncthreads();
    epi_relu(acc, sX, sB + l*128, mq, nq, l31, lh);
  }

  // L7 (panel 8): pre-activation = last_feat
  __syncthreads();
  zero_acc(acc);
  mfma_panel(acc, sX, wsWh + 8*16384, wsWl + 8*16384, mq, nq, l31, lh);

  float* __restrict__ out1 = out + (size_t)NPTS*3;
  #pragma unroll
  for (int tm = 0; tm < 2; ++tm)
    #pragma unroll
    for (int tn = 0; tn < 2; ++tn) {
      const int n = nq*64 + tn*32 + l31;
      const float bv = sB[7*128 + n];
      #pragma unroll
      for (int r = 0; r < 16; ++r) {
        const int row = (r & 3) + 8*(r >> 2) + 4*lh;
        const int m = mq*64 + tm*32 + row;
        const float v = acc[tm][tn][r] + bv;
        out1[(size_t)(g0 + m)*128 + n] = v;
        acc[tm][tn][r] = fmaxf(v, 0.f);
      }
    }

  __syncthreads();                        // all sX reads done; overlay sF
  float* __restrict__ sF = (float*)sX;    // [128][132] fp32
  #pragma unroll
  for (int tm = 0; tm < 2; ++tm)
    #pragma unroll
    for (int tn = 0; tn < 2; ++tn) {
      const int n = nq*64 + tn*32 + l31;
      #pragma unroll
      for (int r = 0; r < 16; ++r) {
        const int row = (r & 3) + 8*(r >> 2) + 4*lh;
        const int m = mq*64 + tm*32 + row;
        sF[m*132 + n] = acc[tm][tn][r];
      }
    }
  __syncthreads();

  for (int pair = tid; pair < 384; pair += 256) {
    const int m = pair / 3, c = pair - m*3;
    const float* __restrict__ xr = sF + m*132;
    const float* __restrict__ wc = sB + 1024 + c*128;
    float a = 0.f;
    #pragma unroll 8
    for (int k = 0; k < 128; ++k) a = fmaf(xr[k], wc[k], a);
    const int g = g0 + m;
    out[g*3 + c] = base3[g*3 + c] + a + sB[1408 + c];
  }
}

extern "C" void kernel_launch(void* const* d_in, const int* in_sizes, int n_in,
                              void* d_out, int out_size, void* d_ws, size_t ws_size,
                              hipStream_t stream)
{
  const float* pts  = (const float*)d_in[0];
  const float* dm   = (const float*)d_in[1];
  const float* cano = (const float*)d_in[2];
  const float* lat  = (const float*)d_in[3];
  const float* w[8]; const float* b[8];
  for (int i = 0; i < 8; ++i) {
    w[i] = (const float*)d_in[4 + 2*i];
    b[i] = (const float*)d_in[5 + 2*i];
  }
  const float* w_out = (const float*)d_in[20];
  const float* b_out = (const float*)d_in[21];
  float* out = (float*)d_out;

  // ws: feat [NPTS][112] uint (29.36MB) | base3 (786KB) | wsWh (288KB) | wsWl (288KB)
  uint_t*   feat  = (uint_t*)d_ws;
  float*    base3 = (float*)((char*)d_ws + (size_t)NPTS*FSTR*4);
  ushort_t* wsWh  = (ushort_t*)((char*)base3 + (size_t)NPTS*3*4);
  ushort_t* wsWl  = wsWh + 147456;

  k_nnfeat<<<1024, 256, 0, stream>>>(pts, dm, cano, lat,
      w[0],w[1],w[2],w[3],w[4],w[5],w[6],w[7], feat, base3, wsWh, wsWl);
  k_mlp<<<NPTS/128, 256, 0, stream>>>(feat, base3, wsWh, wsWl,
      b[0],b[1],b[2],b[3],b[4],b[5],b[6],b[7], w_out, b_out, out);
}